// Round 1
// baseline (309.704 us; speedup 1.0000x reference)
//
#include <hip/hip_runtime.h>
#include <math.h>

// Problem constants (fixed by setup_inputs): N=4, K=11, H=W=256.
#define NB   4
#define KF   11
#define KK   121
#define HH   256
#define WW   256
#define HW   (HH * WW)
#define PADK 5
#define TW   (WW + 2 * PADK)   // 266
#define INVD (1.0f / 255.0f)   // 1/(W-1) == 1/(H-1)

// Pass 1 only: m1 = filter_flow(grid, F).  One block per (n, h) row.
__global__ __launch_bounds__(256) void pass1_kernel(const float* __restrict__ F,
                                                    float* __restrict__ m1) {
    const int n = blockIdx.x / HH;
    const int h = blockIdx.x % HH;
    const int w = threadIdx.x;

    const float* fp = F + (size_t)n * KK * HW + h * WW + w;

    // Per-thread column values/masks (column-bounds only)
    float xv[KF], mk[KF];
#pragma unroll
    for (int kx = 0; kx < KF; ++kx) {
        int cc = w + kx - PADK;
        bool ok = (cc >= 0 && cc < WW);
        xv[kx] = ok ? (float)cc * INVD : 0.0f;
        mk[kx] = ok ? 1.0f : 0.0f;
    }

    float ax = 0.0f, ay = 0.0f;
    for (int ky = 0; ky < KF; ++ky) {
        int rr = h + ky - PADK;
        if (rr < 0 || rr >= HH) continue;  // wave-uniform (h uniform per block)
        float yv = (float)rr * INVD;
        const float* fr = fp + (size_t)ky * KF * HW;
        float srow = 0.0f;
#pragma unroll
        for (int kx = 0; kx < KF; ++kx) {
            float f = fr[(size_t)kx * HW];
            ax = fmaf(f, xv[kx], ax);
            srow = fmaf(f, mk[kx], srow);
        }
        ay = fmaf(yv, srow, ay);
    }

    size_t o = (size_t)n * 2 * HW + h * WW + w;
    m1[o] = ax;
    m1[o + HW] = ay;
}

// Pass 2 (+ optionally fused pass 1 for the other direction).
//   a2 = filter_flow(m1in, F)  -> diff vs grid -> block reduce -> atomicAdd(acc)
//   if FUSE: m1out = filter_flow(grid, F)
template <bool FUSE>
__global__ __launch_bounds__(256) void pass2_kernel(const float* __restrict__ F,
                                                    const float* __restrict__ m1in,
                                                    float* __restrict__ m1out,
                                                    float* __restrict__ acc) {
    __shared__ float tile[2 * KF * TW];  // [ch][ky][col], zero-padded halo
    __shared__ float wsum[4];

    const int n = blockIdx.x / HH;
    const int h = blockIdx.x % HH;
    const int w = threadIdx.x;

    // Stage the 11-row x 266-col x 2-ch neighborhood of m1in into LDS.
    const float* mbase = m1in + (size_t)n * 2 * HW;
    for (int t = threadIdx.x; t < 2 * KF * TW; t += 256) {
        int ch = t / (KF * TW);
        int rem = t - ch * (KF * TW);
        int r = rem / TW;
        int c = rem - r * TW;
        int rr = h + r - PADK;
        int cc = c - PADK;
        float v = 0.0f;
        if (rr >= 0 && rr < HH && cc >= 0 && cc < WW)
            v = mbase[(size_t)ch * HW + rr * WW + cc];
        tile[t] = v;
    }
    __syncthreads();

    const float* fp = F + (size_t)n * KK * HW + h * WW + w;

    float xv[KF], mk[KF];
#pragma unroll
    for (int kx = 0; kx < KF; ++kx) {
        int cc = w + kx - PADK;
        bool ok = (cc >= 0 && cc < WW);
        xv[kx] = ok ? (float)cc * INVD : 0.0f;
        mk[kx] = ok ? 1.0f : 0.0f;
    }

    float a1x = 0.0f, a1y = 0.0f;  // fused pass-1 accumulators
    float a2x = 0.0f, a2y = 0.0f;  // pass-2 accumulators

    for (int ky = 0; ky < KF; ++ky) {
        int rr = h + ky - PADK;
        if (rr < 0 || rr >= HH) continue;  // tile rows there are zero anyway
        float yv = (float)rr * INVD;
        const float* fr = fp + (size_t)ky * KF * HW;
        const float* t0 = tile + ky * TW + w;           // ch 0 (x)
        const float* t1 = t0 + KF * TW;                 // ch 1 (y)
        float srow = 0.0f;
#pragma unroll
        for (int kx = 0; kx < KF; ++kx) {
            float f = fr[(size_t)kx * HW];
            if (FUSE) {
                a1x = fmaf(f, xv[kx], a1x);
                srow = fmaf(f, mk[kx], srow);
            }
            a2x = fmaf(f, t0[kx], a2x);
            a2y = fmaf(f, t1[kx], a2y);
        }
        if (FUSE) a1y = fmaf(yv, srow, a1y);
    }

    if (FUSE) {
        size_t o = (size_t)n * 2 * HW + h * WW + w;
        m1out[o] = a1x;
        m1out[o + HW] = a1y;
    }

    float gx = (float)w * INVD, gy = (float)h * INVD;
    float dx = gx - a2x, dy = gy - a2y;
    float d = sqrtf(dx * dx + dy * dy);

    // wave64 shuffle reduce, then cross-wave via LDS, one atomic per block
#pragma unroll
    for (int off = 32; off > 0; off >>= 1) d += __shfl_down(d, off, 64);
    int lane = threadIdx.x & 63, wid = threadIdx.x >> 6;
    if (lane == 0) wsum[wid] = d;
    __syncthreads();
    if (threadIdx.x == 0) atomicAdd(acc, wsum[0] + wsum[1] + wsum[2] + wsum[3]);
}

__global__ void finalize_kernel(const float* __restrict__ acc, float* __restrict__ out) {
    out[0] = (acc[0] + acc[1]) * (1.0f / ((float)HW * (float)NB));
}

extern "C" void kernel_launch(void* const* d_in, const int* in_sizes, int n_in,
                              void* d_out, int out_size, void* d_ws, size_t ws_size,
                              hipStream_t stream) {
    const float* FA = (const float*)d_in[0];  // FF_AtoB
    const float* FB = (const float*)d_in[1];  // FF_BtoA
    float* out = (float*)d_out;

    float* m1A = (float*)d_ws;                    // [N,2,H,W] = 2 MB
    float* m1B = m1A + (size_t)NB * 2 * HW;       // [N,2,H,W] = 2 MB
    float* acc = m1B + (size_t)NB * 2 * HW;       // 2 floats

    hipMemsetAsync(acc, 0, 2 * sizeof(float), stream);

    dim3 grid(NB * HH), block(256);
    // m1_ABA = flow(grid, F_AtoB)
    pass1_kernel<<<grid, block, 0, stream>>>(FA, m1A);
    // single read of F_BtoA serves BOTH: m2_ABA (-> loss_ABA) and m1_BAB
    pass2_kernel<true><<<grid, block, 0, stream>>>(FB, m1A, m1B, acc);
    // m2_BAB = flow(m1_BAB, F_AtoB) -> loss_BAB
    pass2_kernel<false><<<grid, block, 0, stream>>>(FA, m1B, nullptr, acc + 1);

    finalize_kernel<<<1, 1, 0, stream>>>(acc, out);
}

// Round 2
// 295.086 us; speedup vs baseline: 1.0495x; 1.0495x over previous
//
#include <hip/hip_runtime.h>
#include <math.h>

// Problem constants (fixed by setup_inputs): N=4, K=11, H=W=256.
#define NB    4
#define KF    11
#define KK    121
#define HH    256
#define WW    256
#define HW    (HH * WW)
#define PADK  5
#define TROWS 12                 // rows staged per block (RPB + KF - 1)
#define TW2   268                // padded tile width, multiple of 4 for b64 align
#define INVD  (1.0f / 255.0f)
#define RPB   2                  // output rows per block
#define GRID1 (NB * HH / RPB)    // 512 blocks

// Pass 1: m1 = filter_flow(grid, F). 2 rows/block, 2 px/thread, float2 loads.
__global__ __launch_bounds__(256) void pass1_kernel(const float* __restrict__ F,
                                                    float* __restrict__ m1) {
    const int t   = threadIdx.x;
    const int n   = blockIdx.x / (HH / RPB);
    const int h0  = (blockIdx.x % (HH / RPB)) * RPB;
    const int sub = t >> 7;           // which of the 2 rows
    const int j   = t & 127;
    const int h   = h0 + sub;
    const int w0  = j * 2;

    const float2* fp = (const float2*)(F + (size_t)n * KK * HW + (size_t)h * WW + w0);

    float mk0[KF], mk1[KF];
#pragma unroll
    for (int kx = 0; kx < KF; ++kx) {
        int c0 = w0 + kx - PADK;
        mk0[kx] = (c0 >= 0 && c0 < WW) ? 1.0f : 0.0f;
        mk1[kx] = (c0 + 1 >= 0 && c0 + 1 < WW) ? 1.0f : 0.0f;
    }
    const float b0 = (float)(w0 - PADK) * INVD;  // x-coord base for px0

    float ax0 = 0, ay0 = 0, ax1 = 0, ay1 = 0;
    for (int ky = 0; ky < KF; ++ky) {
        int rr = h + ky - PADK;
        if (rr < 0 || rr >= HH) continue;        // wave-uniform
        float yv = (float)rr * INVD;
        const float2* fr = fp + (size_t)(ky * KF) * (HW / 2);
        float s0 = 0, s1 = 0;
#pragma unroll
        for (int kx = 0; kx < KF; ++kx) {
            float2 f = fr[(size_t)kx * (HW / 2)];
            float u0 = f.x * mk0[kx], u1 = f.y * mk1[kx];
            float xk = b0 + (float)kx * INVD;
            ax0 = fmaf(u0, xk, ax0);
            ax1 = fmaf(u1, xk + INVD, ax1);
            s0 += u0; s1 += u1;
        }
        ay0 = fmaf(yv, s0, ay0);
        ay1 = fmaf(yv, s1, ay1);
    }
    float2* ox = (float2*)(m1 + (size_t)n * 2 * HW + (size_t)h * WW + w0);
    float2* oy = (float2*)(m1 + (size_t)n * 2 * HW + HW + (size_t)h * WW + w0);
    *ox = make_float2(ax0, ax1);
    *oy = make_float2(ay0, ay1);
}

// Pass 2 (+ optionally fused pass 1 for the other direction).
template <bool FUSE>
__global__ __launch_bounds__(256) void pass2_kernel(const float* __restrict__ F,
                                                    const float* __restrict__ m1in,
                                                    float* __restrict__ m1out,
                                                    float* __restrict__ partial) {
    __shared__ float tile[2 * TROWS * TW2];   // [ch][r][c], zero-padded halo
    __shared__ float wsum[4];

    const int t   = threadIdx.x;
    const int n   = blockIdx.x / (HH / RPB);
    const int h0  = (blockIdx.x % (HH / RPB)) * RPB;
    const int sub = t >> 7;
    const int j   = t & 127;
    const int h   = h0 + sub;
    const int w0  = j * 2;

    // Stage 12-row x 268-col x 2-ch m1in neighborhood into LDS.
    const float* mbase = m1in + (size_t)n * 2 * HW;
    for (int i = t; i < 2 * TROWS * TW2; i += 256) {
        int ch  = i / (TROWS * TW2);
        int rem = i - ch * (TROWS * TW2);
        int r   = rem / TW2;
        int c   = rem - r * TW2;
        int rr  = h0 + r - PADK;
        int cc  = c - PADK;
        float v = 0.0f;
        if (rr >= 0 && rr < HH && cc >= 0 && cc < WW)
            v = mbase[(size_t)ch * HW + rr * WW + cc];
        tile[i] = v;
    }
    __syncthreads();

    const float2* fp = (const float2*)(F + (size_t)n * KK * HW + (size_t)h * WW + w0);

    float mk0[KF], mk1[KF];
#pragma unroll
    for (int kx = 0; kx < KF; ++kx) {
        int c0 = w0 + kx - PADK;
        mk0[kx] = (c0 >= 0 && c0 < WW) ? 1.0f : 0.0f;
        mk1[kx] = (c0 + 1 >= 0 && c0 + 1 < WW) ? 1.0f : 0.0f;
    }
    const float b0 = (float)(w0 - PADK) * INVD;

    float a1x0 = 0, a1y0 = 0, a1x1 = 0, a1y1 = 0;
    float a2x0 = 0, a2y0 = 0, a2x1 = 0, a2y1 = 0;

    for (int ky = 0; ky < KF; ++ky) {
        int rr = h + ky - PADK;
        if (rr < 0 || rr >= HH) continue;     // wave-uniform; tile rows zero anyway
        float yv = (float)rr * INVD;
        const float2* fr = fp + (size_t)(ky * KF) * (HW / 2);

        // Register-cache this ky's tile span: cols w0..w0+11, both channels.
        const float* tx = tile + (sub + ky) * TW2 + w0;      // 8B-aligned (TW2%4==0, w0 even)
        const float* ty = tx + TROWS * TW2;
        float cx[12], cy[12];
#pragma unroll
        for (int q = 0; q < 6; ++q) {
            float2 vx = *(const float2*)(tx + 2 * q);
            float2 vy = *(const float2*)(ty + 2 * q);
            cx[2 * q] = vx.x; cx[2 * q + 1] = vx.y;
            cy[2 * q] = vy.x; cy[2 * q + 1] = vy.y;
        }

        float s0 = 0, s1 = 0;
#pragma unroll
        for (int kx = 0; kx < KF; ++kx) {
            float2 f = fr[(size_t)kx * (HW / 2)];
            if (FUSE) {
                float u0 = f.x * mk0[kx], u1 = f.y * mk1[kx];
                float xk = b0 + (float)kx * INVD;
                a1x0 = fmaf(u0, xk, a1x0);
                a1x1 = fmaf(u1, xk + INVD, a1x1);
                s0 += u0; s1 += u1;
            }
            a2x0 = fmaf(f.x, cx[kx], a2x0);
            a2x1 = fmaf(f.y, cx[kx + 1], a2x1);
            a2y0 = fmaf(f.x, cy[kx], a2y0);
            a2y1 = fmaf(f.y, cy[kx + 1], a2y1);
        }
        if (FUSE) {
            a1y0 = fmaf(yv, s0, a1y0);
            a1y1 = fmaf(yv, s1, a1y1);
        }
    }

    if (FUSE) {
        float2* ox = (float2*)(m1out + (size_t)n * 2 * HW + (size_t)h * WW + w0);
        float2* oy = (float2*)(m1out + (size_t)n * 2 * HW + HW + (size_t)h * WW + w0);
        *ox = make_float2(a1x0, a1x1);
        *oy = make_float2(a1y0, a1y1);
    }

    float gx = (float)w0 * INVD, gy = (float)h * INVD;
    float dx0 = gx - a2x0,        dy0 = gy - a2y0;
    float dx1 = gx + INVD - a2x1, dy1 = gy - a2y1;
    float d = sqrtf(dx0 * dx0 + dy0 * dy0) + sqrtf(dx1 * dx1 + dy1 * dy1);

    // block reduce -> one partial per block (no atomics, no zero-init needed)
#pragma unroll
    for (int off = 32; off > 0; off >>= 1) d += __shfl_down(d, off, 64);
    if ((t & 63) == 0) wsum[t >> 6] = d;
    __syncthreads();
    if (t == 0) partial[blockIdx.x] = wsum[0] + wsum[1] + wsum[2] + wsum[3];
}

__global__ __launch_bounds__(256) void finalize_kernel(const float* __restrict__ partial,
                                                       float* __restrict__ out) {
    __shared__ float wsum[4];
    int t = threadIdx.x;
    float s = partial[t] + partial[t + 256] + partial[t + 512] + partial[t + 768];
#pragma unroll
    for (int off = 32; off > 0; off >>= 1) s += __shfl_down(s, off, 64);
    if ((t & 63) == 0) wsum[t >> 6] = s;
    __syncthreads();
    if (t == 0)
        out[0] = (wsum[0] + wsum[1] + wsum[2] + wsum[3]) * (1.0f / ((float)HW * (float)NB));
}

extern "C" void kernel_launch(void* const* d_in, const int* in_sizes, int n_in,
                              void* d_out, int out_size, void* d_ws, size_t ws_size,
                              hipStream_t stream) {
    const float* FA = (const float*)d_in[0];  // FF_AtoB
    const float* FB = (const float*)d_in[1];  // FF_BtoA
    float* out = (float*)d_out;

    float* m1A = (float*)d_ws;                       // [N,2,H,W] = 2 MB
    float* m1B = m1A + (size_t)NB * 2 * HW;          // [N,2,H,W] = 2 MB
    float* partial = m1B + (size_t)NB * 2 * HW;      // 1024 floats, all written every call

    dim3 grid(GRID1), block(256);
    // m1_ABA = flow(grid, F_AtoB)
    pass1_kernel<<<grid, block, 0, stream>>>(FA, m1A);
    // single read of F_BtoA serves BOTH m2_ABA (-> loss) and m1_BAB
    pass2_kernel<true><<<grid, block, 0, stream>>>(FB, m1A, m1B, partial);
    // m2_BAB = flow(m1_BAB, F_AtoB) -> loss
    pass2_kernel<false><<<grid, block, 0, stream>>>(FA, m1B, nullptr, partial + GRID1);

    finalize_kernel<<<1, block, 0, stream>>>(partial, out);
}